// Round 6
// baseline (195.630 us; speedup 1.0000x reference)
//
#include <hip/hip_runtime.h>

#define BATCH 65536
#define TB 32

typedef _Float16 half8 __attribute__((ext_vector_type(8)));
typedef _Float16 half4v __attribute__((ext_vector_type(4)));
typedef _Float16 half2v __attribute__((ext_vector_type(2)));
typedef float fx4 __attribute__((ext_vector_type(4)));
typedef float fx16 __attribute__((ext_vector_type(16)));

// workspace layout (halves) -- unchanged from R12..R17
#define PW1B_OFF 0        // [4][256][32]  W1 base rows (k<110, pad->128)
#define PW1F_OFF 32768    // [256][32]     W1 feat rows, k-map [feat_i(15) 0 feat_j(15) 0]
#define PW2_OFF  40960    // [8][256][32]
#define PWR_OFF  106496   // [8][256][32]
#define PWH_OFF  172032   // [8][16][32]   [mean_w | lstd_w | pad]
#define WS_TOTAL 176128

__global__ __launch_bounds__(256) void prep_weights(
    const float* __restrict__ w1, const float* __restrict__ w2,
    const float* __restrict__ wr, const float* __restrict__ wm,
    const float* __restrict__ wl, _Float16* __restrict__ ws)
{
  int idx = blockIdx.x * 256 + threadIdx.x;
  if (idx < 32768) {            // pw1b
    int kk = idx & 31, n = (idx >> 5) & 255, kt = idx >> 13;
    int k = kt * 32 + kk;
    ws[idx] = (k < 110) ? (_Float16)w1[k * 256 + n] : (_Float16)0.f;
  } else if (idx < 40960) {     // pw1f
    int t = idx - 32768;
    int kk = t & 31, n = t >> 5;
    _Float16 v = (_Float16)0.f;
    if (kk < 15)                  v = (_Float16)w1[(113 + kk) * 256 + n];
    else if (kk >= 16 && kk < 31) v = (_Float16)w1[(131 + (kk - 16)) * 256 + n];
    ws[idx] = v;
  } else if (idx < 106496) {    // pw2
    int t = idx - 40960;
    int kk = t & 31, n = (t >> 5) & 255, kt = t >> 13;
    ws[idx] = (_Float16)w2[(kt * 32 + kk) * 256 + n];
  } else if (idx < 172032) {    // pwr
    int t = idx - 106496;
    int kk = t & 31, n = (t >> 5) & 255, kt = t >> 13;
    ws[idx] = (_Float16)wr[(kt * 32 + kk) * 256 + n];
  } else if (idx < WS_TOTAL) {  // pwh
    int t = idx - 172032;
    int kk = t & 31, n = (t >> 5) & 15, kt = t >> 9;
    int k = kt * 32 + kk;
    _Float16 v = (_Float16)0.f;
    if (n < 4) v = (_Float16)wm[k * 4 + n];
    else if (n < 8) v = (_Float16)wl[k * 4 + (n - 4)];
    ws[PWH_OFF + t] = v;
  }
}

// R18 = R17 with g2 converted to 32x32x16 MFMAs.
// Rationale (R17 counters): only ~43% of SIMD issue slots are used; VALU and
// MFMA instruction COUNT is the co-limiter with latency. g2 is 192 of 264
// MFMAs/wave; as 32x32x16 it is 96 MFMAs (one 32col x 32row D-tile per perm,
// K=256 in 16 steps), with ONE shared pw2 A-load per kt for 2 interleaved
// perms. Existing ws layout serves 32x32 A-frags (lane->col=lane&31,
// k-oct=lane>>5); H1/Bb serve B-frags conflict-free. D-layout (m74/m101:
// col=lane&31, row=(reg&3)+8*(reg>>2)+4*(lane>>5)) makes the perm-sum
// layout-agnostic (agg[i]+=relu(acc[i])) and agg->Bb staging 4 packed b64
// writes in the SAME Bb layout g3 already reads -> g3/heads/U/g1 unchanged.
// agg carried packed fp16 (8 regs, proven safe R15/R17). b2 bias deferred to
// epilogue. Reg budget passA: acc0+acc1 32 + aggp 8 + u 16 accum, arch ~50
// -> total ~105 <= 128 -> 2 blocks/CU, no spill.
__global__ __launch_bounds__(512) void actor_fused(
    const float* __restrict__ obs, const float* __restrict__ lemb,
    const float* __restrict__ w1, const _Float16* __restrict__ ws,
    const float* __restrict__ b1, const float* __restrict__ b2,
    const float* __restrict__ br, const float* __restrict__ bm,
    const float* __restrict__ bl, float* __restrict__ out)
{
  __shared__ __align__(16) _Float16 H1[6 * 16 * 256]; // 48 KB: 6 tiles (pp*2+rt); tiles 0,1 later r
  __shared__ __align__(16) _Float16 Bb[32 * 256];     // 16 KB: base (K=128), then agg
  __shared__ __align__(16) _Float16 Os[3 * 32 * 16];  //  3 KB: compact obj tiles
  __shared__ __align__(16) float    Bsf[6 * 256];     //  6 KB: fused per-perm biases (f32)

  const _Float16* __restrict__ pw1b = ws + PW1B_OFF;
  const _Float16* __restrict__ pw1f = ws + PW1F_OFF;
  const _Float16* __restrict__ pw2  = ws + PW2_OFF;
  const _Float16* __restrict__ pwr  = ws + PWR_OFF;
  const _Float16* __restrict__ pwh  = ws + PWH_OFF;

  const int tid  = threadIdx.x;
  const int wave = tid >> 6;        // 0..7
  const int lane = tid & 63;
  const int q    = lane >> 4;
  const int l16  = lane & 15;
  const int m31  = lane & 31;       // 32x32: out-col (A) / batch-row (B)
  const int koct = lane >> 5;       // 32x32: k-octet select
  const int colbase = wave * 32;    // this wave's 32 output cols
  const int cb8  = colbase >> 3;
  const int rowbase = blockIdx.x * TB;

  const int c0_0 = colbase + q * 4;        // 16x16 packs (g1/g3 epilogues)
  const int c0_1 = colbase + 16 + q * 4;

  // ---- stage base (32 rows x K=128) -- wave-contiguous, conflict-free ----
  for (int idx = tid; idx < 1024; idx += 512) {
    int oct = idx >> 6;          // 0..15 (= k-octet)
    int r   = (idx >> 1) & 31;   // row
    int hf  = idx & 1;           // which 4-col half of the octet
    int c   = oct * 8 + hf * 4;
    float v0, v1, v2, v3;
    if (c + 3 < 100) {
      float4 f = *(const float4*)(lemb + (rowbase + r) * 100 + c);
      v0 = f.x; v1 = f.y; v2 = f.z; v3 = f.w;
    } else {
      const float* orow = obs + (rowbase + r) * 55;
      const float* lrow = lemb + (rowbase + r) * 100;
      float t[4];
      #pragma unroll
      for (int j = 0; j < 4; ++j) {
        int cc = c + j;
        t[j] = cc < 100 ? lrow[cc] : (cc < 110 ? orow[cc - 100] : 0.f);
      }
      v0 = t[0]; v1 = t[1]; v2 = t[2]; v3 = t[3];
    }
    half4v hv = {(_Float16)v0, (_Float16)v1, (_Float16)v2, (_Float16)v3};
    *(half4v*)&Bb[(oct * 32 + r) * 8 + hf * 4] = hv;
  }
  // ---- compact obj tiles: 3 obj x 2 k-octets x 32 rows, 8B per lane ----
  for (int idx = tid; idx < 384; idx += 512) {
    int o   = idx >> 7;          // 0..2
    int k4i = (idx >> 5) & 3;    // which 4-k group
    int r   = idx & 31;
    int k0  = k4i * 4;
    const float* frow = obs + (rowbase + r) * 55 + 10 + o * 15;
    float t[4];
    #pragma unroll
    for (int j = 0; j < 4; ++j) {
      int k = k0 + j;
      t[j] = (k < 15) ? frow[k] : 0.f;
    }
    half4v hv = {(_Float16)t[0], (_Float16)t[1], (_Float16)t[2], (_Float16)t[3]};
    *(half4v*)&Os[o * 512 + ((k0 >> 3) * 32 + r) * 8 + (k0 & 7)] = hv;
  }
  // ---- fused per-perm biases (f32): b1 + W1[onehot_i row] + W1[onehot_j row] ----
  for (int idx = tid; idx < 1536; idx += 512) {
    int p = idx >> 8, c = idx & 255;
    int oi = p >> 1, oj = (1161 >> (2 * p)) & 3;
    Bsf[idx] = b1[c] + w1[(110 + oi) * 256 + c] + w1[(128 + oj) * 256 + c];
  }
  __syncthreads();  // B1

  const fx4 zero4 = {0.f, 0.f, 0.f, 0.f};

  // ---- U = (base @ W1base)^T tiles (K=128), computed ONCE, held in regs ----
  fx4 u[4];  // [rt*2+nt]
  u[0] = zero4; u[1] = zero4; u[2] = zero4; u[3] = zero4;
  #pragma unroll
  for (int kt = 0; kt < 4; ++kt) {
    half8 a0 = *(const half8*)&Bb[((kt * 4 + q) * 32 + l16) * 8];
    half8 a1 = *(const half8*)&Bb[((kt * 4 + q) * 32 + 16 + l16) * 8];
    #pragma unroll
    for (int nt = 0; nt < 2; ++nt) {
      half8 b = *(const half8*)&pw1b[(kt * 256 + colbase + nt * 16 + l16) * 32 + q * 8];
      u[nt]     = __builtin_amdgcn_mfma_f32_16x16x32_f16(b, a0, u[nt], 0, 0, 0);
      u[2 + nt] = __builtin_amdgcn_mfma_f32_16x16x32_f16(b, a1, u[2 + nt], 0, 0, 0);
    }
  }
  // no barrier: Bb not rewritten until agg staging (post-B4); H1 unread so far

  // ---- GEMM1 group: h1_p = relu(U + F_p @ W1f + bias_p), perms {3g..3g+2} ----
  auto g1_group = [&](int g) {
    half8 b1f0 = *(const half8*)&pw1f[(colbase + l16) * 32 + q * 8];
    half8 b1f1 = *(const half8*)&pw1f[(colbase + 16 + l16) * 32 + q * 8];
    #pragma unroll
    for (int pp = 0; pp < 3; ++pp) {
      const int p = g * 3 + pp;
      const int oi = p >> 1, oj = (1161 >> (2 * p)) & 3;
      const int o = (q < 2) ? oi : oj;   // quads 0,1 -> feat_i; 2,3 -> feat_j
      #pragma unroll
      for (int rt = 0; rt < 2; ++rt) {
        half8 af = *(const half8*)&Os[o * 512 + ((q & 1) * 32 + rt * 16 + l16) * 8];
        #pragma unroll
        for (int nt = 0; nt < 2; ++nt) {
          fx4 t = __builtin_amdgcn_mfma_f32_16x16x32_f16(nt ? b1f1 : b1f0, af,
                                                         u[rt * 2 + nt], 0, 0, 0);
          const int c0 = nt ? c0_1 : c0_0;
          fx4 bs = *(const fx4*)&Bsf[p * 256 + c0];
          half4v hv = {(_Float16)fmaxf(t[0] + bs[0], 0.f),
                       (_Float16)fmaxf(t[1] + bs[1], 0.f),
                       (_Float16)fmaxf(t[2] + bs[2], 0.f),
                       (_Float16)fmaxf(t[3] + bs[3], 0.f)};
          *(half4v*)&H1[(pp * 2 + rt) * 4096 + ((c0 >> 3) * 16 + l16) * 8 + (c0 & 7)] = hv;
        }
      }
    }
  };

  // ---- running agg, packed fp16 (8 VGPRs); element i of the 32x32 D-tile ----
  half4v aggp[4];
  {
    half4v z = {(_Float16)0.f, (_Float16)0.f, (_Float16)0.f, (_Float16)0.f};
    aggp[0] = z; aggp[1] = z; aggp[2] = z; aggp[3] = z;
  }

  // ---- GEMM2 group (32x32x16): pass A = 2 perms interleaved (shared A-frag
  // per kt), pass B = 3rd perm. K=256 in 16 steps. Bias deferred to epilogue.
  const int brt = m31 >> 4;       // B-frag row-tile
  const int r16 = m31 & 15;
  auto g2_group = [&](int g) {
    (void)g;
    // pass A: perms (in-group) 0,1
    fx16 acc0, acc1;
    #pragma unroll
    for (int i = 0; i < 16; ++i) { acc0[i] = 0.f; acc1[i] = 0.f; }
    #pragma unroll
    for (int kt = 0; kt < 16; ++kt) {
      half8 aW = *(const half8*)&pw2[((kt >> 1) * 256 + colbase + m31) * 32 + (kt & 1) * 16 + koct * 8];
      half8 x0 = *(const half8*)&H1[(0 * 2 + brt) * 4096 + ((kt * 2 + koct) * 16 + r16) * 8];
      half8 x1 = *(const half8*)&H1[(1 * 2 + brt) * 4096 + ((kt * 2 + koct) * 16 + r16) * 8];
      acc0 = __builtin_amdgcn_mfma_f32_32x32x16_f16(aW, x0, acc0, 0, 0, 0);
      acc1 = __builtin_amdgcn_mfma_f32_32x32x16_f16(aW, x1, acc1, 0, 0, 0);
    }
    {
      fx4 bvq[4];
      #pragma unroll
      for (int rq = 0; rq < 4; ++rq) bvq[rq] = *(const fx4*)&b2[colbase + rq * 8 + koct * 4];
      #pragma unroll
      for (int rq = 0; rq < 4; ++rq) {
        half4v hp = aggp[rq];
        #pragma unroll
        for (int j = 0; j < 4; ++j) {
          int i = rq * 4 + j;
          float b = bvq[rq][j];
          float s = (float)hp[j] + fmaxf(acc0[i] + b, 0.f) + fmaxf(acc1[i] + b, 0.f);
          hp[j] = (_Float16)s;
        }
        aggp[rq] = hp;
      }
    }
    // pass B: perm (in-group) 2
    fx16 acc2;
    #pragma unroll
    for (int i = 0; i < 16; ++i) acc2[i] = 0.f;
    #pragma unroll
    for (int kt = 0; kt < 16; ++kt) {
      half8 aW = *(const half8*)&pw2[((kt >> 1) * 256 + colbase + m31) * 32 + (kt & 1) * 16 + koct * 8];
      half8 x2 = *(const half8*)&H1[(2 * 2 + brt) * 4096 + ((kt * 2 + koct) * 16 + r16) * 8];
      acc2 = __builtin_amdgcn_mfma_f32_32x32x16_f16(aW, x2, acc2, 0, 0, 0);
    }
    {
      fx4 bvq[4];
      #pragma unroll
      for (int rq = 0; rq < 4; ++rq) bvq[rq] = *(const fx4*)&b2[colbase + rq * 8 + koct * 4];
      #pragma unroll
      for (int rq = 0; rq < 4; ++rq) {
        half4v hp = aggp[rq];
        #pragma unroll
        for (int j = 0; j < 4; ++j) {
          int i = rq * 4 + j;
          float s = (float)hp[j] + fmaxf(acc2[i] + bvq[rq][j], 0.f);
          hp[j] = (_Float16)s;
        }
        aggp[rq] = hp;
      }
    }
  };

  g1_group(0);
  __syncthreads();  // B2: h1 perms 0-2 ready (and all U reads of Bb done)
  g2_group(0);
  __syncthreads();  // B3: all H1 reads of group 0 done
  g1_group(1);
  __syncthreads();  // B4: h1 perms 3-5 ready
  g2_group(1);

  // stage agg into Bb (base region dead: all waves past B4 > their U reads).
  // 32x32 D element i=(rq*4+j) lives at col c0 = colbase + 8*rq + 4*koct + j,
  // row n = m31 -> same Bb layout g3 already reads. 4 packed b64 writes.
  #pragma unroll
  for (int rq = 0; rq < 4; ++rq)
    *(half4v*)&Bb[((cb8 + rq) * 32 + m31) * 8 + koct * 4] = aggp[rq];
  __syncthreads();  // B5: agg complete in Bb; all H1 reads done

  // ---- GEMM3: r = relu(agg @ rho + br), M=32, K=256; r -> H1 tiles 0,1 ----
  fx4 acc3[4];  // [rt*2+nt]
  {
    fx4 brv0 = *(const fx4*)&br[c0_0];
    fx4 brv1 = *(const fx4*)&br[c0_1];
    acc3[0] = brv0; acc3[1] = brv1; acc3[2] = brv0; acc3[3] = brv1;
  }
  #pragma unroll 2
  for (int kt = 0; kt < 8; ++kt) {
    half8 a0 = *(const half8*)&Bb[((kt * 4 + q) * 32 + l16) * 8];
    half8 a1 = *(const half8*)&Bb[((kt * 4 + q) * 32 + 16 + l16) * 8];
    half8 b0 = *(const half8*)&pwr[(kt * 256 + colbase + l16) * 32 + q * 8];
    half8 b1h = *(const half8*)&pwr[(kt * 256 + colbase + 16 + l16) * 32 + q * 8];
    acc3[0] = __builtin_amdgcn_mfma_f32_16x16x32_f16(b0,  a0, acc3[0], 0, 0, 0);
    acc3[1] = __builtin_amdgcn_mfma_f32_16x16x32_f16(b1h, a0, acc3[1], 0, 0, 0);
    acc3[2] = __builtin_amdgcn_mfma_f32_16x16x32_f16(b0,  a1, acc3[2], 0, 0, 0);
    acc3[3] = __builtin_amdgcn_mfma_f32_16x16x32_f16(b1h, a1, acc3[3], 0, 0, 0);
  }
  #pragma unroll
  for (int rt = 0; rt < 2; ++rt)
    #pragma unroll
    for (int nt = 0; nt < 2; ++nt) {
      const int c0 = nt ? c0_1 : c0_0;
      fx4 t = acc3[rt * 2 + nt];
      half4v hv = {(_Float16)fmaxf(t[0], 0.f), (_Float16)fmaxf(t[1], 0.f),
                   (_Float16)fmaxf(t[2], 0.f), (_Float16)fmaxf(t[3], 0.f)};
      *(half4v*)&H1[rt * 4096 + ((c0 >> 3) * 16 + l16) * 8 + (c0 & 7)] = hv;
    }
  __syncthreads();  // B6: r ready

  // ---- heads: waves 0,1 (one row-half each); swapped D -> float4 stores ----
  if (wave < 2) {
    fx4 a4 = zero4;
    #pragma unroll 2
    for (int kt = 0; kt < 8; ++kt) {
      half8 rfrag = *(const half8*)&H1[wave * 4096 + ((kt * 4 + q) * 16 + l16) * 8];
      half8 wfrag = *(const half8*)&pwh[(kt * 16 + l16) * 32 + q * 8];
      a4 = __builtin_amdgcn_mfma_f32_16x16x32_f16(wfrag, rfrag, a4, 0, 0, 0);
    }
    const int row = rowbase + wave * 16 + l16;
    if (q == 0) {            // head cols 0..3 = mean
      fx4 bm4 = *(const fx4*)bm;
      fx4 o = {a4[0] + bm4[0], a4[1] + bm4[1], a4[2] + bm4[2], a4[3] + bm4[3]};
      *(fx4*)&out[row * 4] = o;
    } else if (q == 1) {     // head cols 4..7 = log_std (clipped)
      fx4 bl4 = *(const fx4*)bl;
      fx4 o;
      #pragma unroll
      for (int rr = 0; rr < 4; ++rr) {
        float v = a4[rr] + bl4[rr];
        o[rr] = v < -20.f ? -20.f : (v > 2.f ? 2.f : v);
      }
      *(fx4*)&out[BATCH * 4 + row * 4] = o;
    }
  }
}

extern "C" void kernel_launch(void* const* d_in, const int* in_sizes, int n_in,
                              void* d_out, int out_size, void* d_ws, size_t ws_size,
                              hipStream_t stream) {
  const float* obs  = (const float*)d_in[0];
  const float* lemb = (const float*)d_in[1];
  const float* w1   = (const float*)d_in[2];
  const float* b1   = (const float*)d_in[3];
  const float* w2   = (const float*)d_in[4];
  const float* b2   = (const float*)d_in[5];
  const float* wr   = (const float*)d_in[6];
  const float* br   = (const float*)d_in[7];
  const float* wm   = (const float*)d_in[8];
  const float* bm   = (const float*)d_in[9];
  const float* wl   = (const float*)d_in[10];
  const float* bl   = (const float*)d_in[11];
  float* out = (float*)d_out;
  _Float16* ws = (_Float16*)d_ws;

  hipLaunchKernelGGL(prep_weights, dim3(WS_TOTAL / 256), dim3(256), 0, stream,
                     w1, w2, wr, wm, wl, ws);
  hipLaunchKernelGGL(actor_fused, dim3(BATCH / TB), dim3(512), 0, stream,
                     obs, lemb, w1, (const _Float16*)ws, b1, b2, br, bm, bl, out);
}